// Round 6
// baseline (175.931 us; speedup 1.0000x reference)
//
#include <hip/hip_runtime.h>
#include <hip/hip_bf16.h>

// GAT layer, N=8192, F_IN=256, F_OUT=64.
//  k0 : pack W (256x64 f32) -> Wfrag bf16 B-fragments (one-time, 32 KB).
//  k1 : Wh = h@W via MFMA (16 rows/wave, Wfrag reuse); f,g projections from
//       accumulators; Bpack (bf16 B-frags of Wh).
//  k2a: pure-stream mask builder (nontemporal adj loads).
//       ML[i][c][q] bit l = adj[i][c*256 + l*4 + q] > 0.
//  k2b: U = adj@Wh from bitmask via MFMA; 32 rows/block (dual row-set shares
//       fragment loads); masked Gmax; writes Upack (bf16 B-frags) + Gmax.
//  k3 : fused softmax weights + attention@U via MFMA + denominator; ELU.
//       Same 32-row dual-set structure.
//
// Fragment convention (proven rounds 1/3/4/5):
//  element e of lane l <-> k = kblock*32 + (l>>4)*8 + e; A row / B col = l&15;
//  C/D: col = l&15, row = (l>>4)*4 + reg.
//  Bpack/Upack/Wfrag: frag[(kb*4+b)*64 + lane][e]  (s16x8 per lane)
// Mask bit for (row i, col j): word ML[i*128 + (j>>8)*4 + (j&3)], bit (j>>2)&63.
//  For fragment element (r, jb, kg, e): word (jb>>3)*4 + (e&3),
//  shift = (jb&7)*8 + kg*2 + (e>>2).

#define N 8192

typedef float f32x4 __attribute__((ext_vector_type(4)));
typedef short s16x8 __attribute__((ext_vector_type(8)));
typedef unsigned long long u64;
typedef u64 u64x2 __attribute__((ext_vector_type(2)));

__device__ __forceinline__ unsigned short f2bf(float x) {
  unsigned u = __float_as_uint(x);
  u += 0x7FFFu + ((u >> 16) & 1u);   // RNE
  return (unsigned short)(u >> 16);
}
__device__ __forceinline__ unsigned pack2(unsigned short lo, unsigned short hi) {
  return (unsigned)lo | ((unsigned)hi << 16);
}

#define MFMA __builtin_amdgcn_mfma_f32_16x16x32_bf16

// ---------------- k0: W -> Wfrag (bf16 B-fragments) ----------------
__global__ __launch_bounds__(64) void k0(const float* __restrict__ W,
                                         unsigned short* __restrict__ Wfrag) {
  const int l = threadIdx.x;
  const int kb = blockIdx.x >> 2;          // 0..7
  const int b = blockIdx.x & 3;            // 0..3
  const int r = l & 15, kg = l >> 4;
  s16x8 v;
#pragma unroll
  for (int e = 0; e < 8; ++e)
    v[e] = (short)f2bf(W[(size_t)((kb << 5) + (kg << 3) + e) * 64 + (b << 4) + r]);
  ((s16x8*)Wfrag)[(size_t)blockIdx.x * 64 + l] = v;
}

// ---------------- k1: Wh via MFMA, f, g, Bpack ----------------
__global__ __launch_bounds__(64) void k1(const float* __restrict__ h,
                                         const unsigned short* __restrict__ Wfrag,
                                         const float* __restrict__ a,
                                         unsigned short* __restrict__ Bpack,
                                         float* __restrict__ f,
                                         float* __restrict__ g) {
  const int l = threadIdx.x;
  const int r = l & 15, kg = l >> 4;
  const int i0 = blockIdx.x << 4;          // 16 rows per wave
  const s16x8* Wv = (const s16x8*)Wfrag;
  f32x4 A0 = {0.f,0.f,0.f,0.f}, A1 = A0, A2 = A0, A3 = A0;
  const float* hp0 = h + (size_t)(i0 + r) * 256 + (kg << 3);
#pragma unroll
  for (int kb = 0; kb < 8; ++kb) {
    const float* hp = hp0 + (kb << 5);
    f32x4 h0 = *(const f32x4*)hp;
    f32x4 h1 = *(const f32x4*)(hp + 4);
    s16x8 af;
    af[0] = (short)f2bf(h0.x); af[1] = (short)f2bf(h0.y);
    af[2] = (short)f2bf(h0.z); af[3] = (short)f2bf(h0.w);
    af[4] = (short)f2bf(h1.x); af[5] = (short)f2bf(h1.y);
    af[6] = (short)f2bf(h1.z); af[7] = (short)f2bf(h1.w);
    const size_t wi = ((size_t)kb << 8) + l;
    A0 = MFMA(af, Wv[wi      ], A0, 0, 0, 0);
    A1 = MFMA(af, Wv[wi +  64], A1, 0, 0, 0);
    A2 = MFMA(af, Wv[wi + 128], A2, 0, 0, 0);
    A3 = MFMA(af, Wv[wi + 192], A3, 0, 0, 0);
  }
  f32x4 Aarr[4] = {A0, A1, A2, A3};
  float av[4], bv[4];
#pragma unroll
  for (int b = 0; b < 4; ++b) { av[b] = a[(b << 4) + r]; bv[b] = a[64 + (b << 4) + r]; }
#pragma unroll
  for (int q = 0; q < 4; ++q) {
    float s1 = Aarr[0][q] * av[0] + Aarr[1][q] * av[1]
             + Aarr[2][q] * av[2] + Aarr[3][q] * av[3];
    float s2 = Aarr[0][q] * bv[0] + Aarr[1][q] * bv[1]
             + Aarr[2][q] * bv[2] + Aarr[3][q] * bv[3];
#pragma unroll
    for (int d = 1; d < 16; d <<= 1) {
      s1 += __shfl_xor(s1, d);
      s2 += __shfl_xor(s2, d);
    }
    if (r == 0) {
      f[i0 + (kg << 2) + q] = s1;
      g[i0 + (kg << 2) + q] = s2;
    }
  }
#pragma unroll
  for (int b = 0; b < 4; ++b) {
#pragma unroll
    for (int p = 0; p < 2; ++p) {
      const int k0r = i0 + (kg << 2) + (p << 1);
      const unsigned pkv = pack2(f2bf(Aarr[b][p << 1]), f2bf(Aarr[b][(p << 1) + 1]));
      const int kbD = k0r >> 5, lgrp = (k0r >> 3) & 3, e0 = k0r & 7;
      *(unsigned*)((char*)Bpack +
          ((size_t)((kbD << 2) + b) * 64 + (r | (lgrp << 4))) * 16 + (e0 << 1)) = pkv;
    }
  }
}

// ---------------- k2a: pure-stream bitmask builder ----------------
__global__ __launch_bounds__(256, 8) void k2a(const float* __restrict__ adj,
                                              u64* __restrict__ ML) {
  const int l = threadIdx.x & 63;
  const int w = threadIdx.x >> 6;
  const int i = (blockIdx.x << 2) + w;     // one row per wave
  const float* ap = adj + (size_t)i * N + (l << 2);
  u64* mp = ML + (size_t)i * 128;
  for (int cc = 0; cc < 32; cc += 4) {
    f32x4 v0 = __builtin_nontemporal_load((const f32x4*)(ap + ((cc + 0) << 8)));
    f32x4 v1 = __builtin_nontemporal_load((const f32x4*)(ap + ((cc + 1) << 8)));
    f32x4 v2 = __builtin_nontemporal_load((const f32x4*)(ap + ((cc + 2) << 8)));
    f32x4 v3 = __builtin_nontemporal_load((const f32x4*)(ap + ((cc + 3) << 8)));
    u64 b0  = __ballot(v0.x > 0.f), b1  = __ballot(v0.y > 0.f);
    u64 b2  = __ballot(v0.z > 0.f), b3  = __ballot(v0.w > 0.f);
    u64 b4  = __ballot(v1.x > 0.f), b5  = __ballot(v1.y > 0.f);
    u64 b6  = __ballot(v1.z > 0.f), b7  = __ballot(v1.w > 0.f);
    u64 b8  = __ballot(v2.x > 0.f), b9  = __ballot(v2.y > 0.f);
    u64 b10 = __ballot(v2.z > 0.f), b11 = __ballot(v2.w > 0.f);
    u64 b12 = __ballot(v3.x > 0.f), b13 = __ballot(v3.y > 0.f);
    u64 b14 = __ballot(v3.z > 0.f), b15 = __ballot(v3.w > 0.f);
    if (l == 0) {
      u64x2* q = (u64x2*)(mp + (cc << 2));
      u64x2 t0; t0.x = b0;  t0.y = b1;  q[0] = t0;
      u64x2 t1; t1.x = b2;  t1.y = b3;  q[1] = t1;
      u64x2 t2; t2.x = b4;  t2.y = b5;  q[2] = t2;
      u64x2 t3; t3.x = b6;  t3.y = b7;  q[3] = t3;
      u64x2 t4; t4.x = b8;  t4.y = b9;  q[4] = t4;
      u64x2 t5; t5.x = b10; t5.y = b11; q[5] = t5;
      u64x2 t6; t6.x = b12; t6.y = b13; q[6] = t6;
      u64x2 t7; t7.x = b14; t7.y = b15; q[7] = t7;
    }
  }
}

// ---------------- k2b: U = adj@Wh from mask + Gmax; 32 rows/block ----------------
__global__ __launch_bounds__(1024) void k2b(const u64* __restrict__ ML,
                                            const unsigned short* __restrict__ Bpack,
                                            const float* __restrict__ g,
                                            unsigned short* __restrict__ Upack,
                                            float* __restrict__ Gmax) {
  __shared__ float red[2][16][64][16];   // 128 KB
  __shared__ float gred[2][16][16];      // 2 KB
  const int l = threadIdx.x & 63;
  const int w = threadIdx.x >> 6;        // 0..15
  const int i0 = blockIdx.x << 5;        // 32 rows/block
  const int r = l & 15, kg = l >> 4;
  const s16x8* Bv = (const s16x8*)Bpack;
  const u64x2* mrow0 = (const u64x2*)(ML + (size_t)(i0 + r) * 128);
  const u64x2* mrow1 = (const u64x2*)(ML + (size_t)(i0 + 16 + r) * 128);
  const int sh0 = kg << 1;
  f32x4 a00 = {0.f,0.f,0.f,0.f}, a01 = a00, a02 = a00, a03 = a00;
  f32x4 a10 = a00, a11 = a00, a12 = a00, a13 = a00;
  float gmx0 = -INFINITY, gmx1 = -INFINITY;
  for (int cc = 0; cc < 2; ++cc) {
    const int c = (w << 1) + cc;         // chunk of 256 cols
    u64x2 xm01 = mrow0[(c << 1)], xm23 = mrow0[(c << 1) + 1];
    u64x2 ym01 = mrow1[(c << 1)], ym23 = mrow1[(c << 1) + 1];
    const u64 x0 = xm01.x, x1 = xm01.y, x2 = xm23.x, x3 = xm23.y;
    const u64 y0 = ym01.x, y1 = ym01.y, y2 = ym23.x, y3 = ym23.y;
#pragma unroll
    for (int j7 = 0; j7 < 8; ++j7) {
      const int jb = (c << 3) + j7;
      f32x4 g0 = *(const f32x4*)(g + (jb << 5) + (kg << 3));
      f32x4 g1 = *(const f32x4*)(g + (jb << 5) + (kg << 3) + 4);
      const int shb = (j7 << 3) + sh0;
      const unsigned p0 = (unsigned)(x0 >> shb) & 1u;
      const unsigned p1 = (unsigned)(x1 >> shb) & 1u;
      const unsigned p2 = (unsigned)(x2 >> shb) & 1u;
      const unsigned p3 = (unsigned)(x3 >> shb) & 1u;
      const unsigned p4 = (unsigned)(x0 >> (shb + 1)) & 1u;
      const unsigned p5 = (unsigned)(x1 >> (shb + 1)) & 1u;
      const unsigned p6 = (unsigned)(x2 >> (shb + 1)) & 1u;
      const unsigned p7 = (unsigned)(x3 >> (shb + 1)) & 1u;
      const unsigned q0 = (unsigned)(y0 >> shb) & 1u;
      const unsigned q1 = (unsigned)(y1 >> shb) & 1u;
      const unsigned q2 = (unsigned)(y2 >> shb) & 1u;
      const unsigned q3 = (unsigned)(y3 >> shb) & 1u;
      const unsigned q4 = (unsigned)(y0 >> (shb + 1)) & 1u;
      const unsigned q5 = (unsigned)(y1 >> (shb + 1)) & 1u;
      const unsigned q6 = (unsigned)(y2 >> (shb + 1)) & 1u;
      const unsigned q7 = (unsigned)(y3 >> (shb + 1)) & 1u;
      s16x8 af0, af1;
      af0[0] = p0 ? (short)0x3F80 : (short)0;
      af0[1] = p1 ? (short)0x3F80 : (short)0;
      af0[2] = p2 ? (short)0x3F80 : (short)0;
      af0[3] = p3 ? (short)0x3F80 : (short)0;
      af0[4] = p4 ? (short)0x3F80 : (short)0;
      af0[5] = p5 ? (short)0x3F80 : (short)0;
      af0[6] = p6 ? (short)0x3F80 : (short)0;
      af0[7] = p7 ? (short)0x3F80 : (short)0;
      af1[0] = q0 ? (short)0x3F80 : (short)0;
      af1[1] = q1 ? (short)0x3F80 : (short)0;
      af1[2] = q2 ? (short)0x3F80 : (short)0;
      af1[3] = q3 ? (short)0x3F80 : (short)0;
      af1[4] = q4 ? (short)0x3F80 : (short)0;
      af1[5] = q5 ? (short)0x3F80 : (short)0;
      af1[6] = q6 ? (short)0x3F80 : (short)0;
      af1[7] = q7 ? (short)0x3F80 : (short)0;
      if (p0) gmx0 = fmaxf(gmx0, g0.x);
      if (p1) gmx0 = fmaxf(gmx0, g0.y);
      if (p2) gmx0 = fmaxf(gmx0, g0.z);
      if (p3) gmx0 = fmaxf(gmx0, g0.w);
      if (p4) gmx0 = fmaxf(gmx0, g1.x);
      if (p5) gmx0 = fmaxf(gmx0, g1.y);
      if (p6) gmx0 = fmaxf(gmx0, g1.z);
      if (p7) gmx0 = fmaxf(gmx0, g1.w);
      if (q0) gmx1 = fmaxf(gmx1, g0.x);
      if (q1) gmx1 = fmaxf(gmx1, g0.y);
      if (q2) gmx1 = fmaxf(gmx1, g0.z);
      if (q3) gmx1 = fmaxf(gmx1, g0.w);
      if (q4) gmx1 = fmaxf(gmx1, g1.x);
      if (q5) gmx1 = fmaxf(gmx1, g1.y);
      if (q6) gmx1 = fmaxf(gmx1, g1.z);
      if (q7) gmx1 = fmaxf(gmx1, g1.w);
      const size_t bi = ((size_t)jb << 8) + l;
      s16x8 f0 = Bv[bi], f1 = Bv[bi + 64], f2 = Bv[bi + 128], f3 = Bv[bi + 192];
      a00 = MFMA(af0, f0, a00, 0, 0, 0);
      a01 = MFMA(af0, f1, a01, 0, 0, 0);
      a02 = MFMA(af0, f2, a02, 0, 0, 0);
      a03 = MFMA(af0, f3, a03, 0, 0, 0);
      a10 = MFMA(af1, f0, a10, 0, 0, 0);
      a11 = MFMA(af1, f1, a11, 0, 0, 0);
      a12 = MFMA(af1, f2, a12, 0, 0, 0);
      a13 = MFMA(af1, f3, a13, 0, 0, 0);
    }
  }
  gmx0 = fmaxf(gmx0, __shfl_xor(gmx0, 16));
  gmx0 = fmaxf(gmx0, __shfl_xor(gmx0, 32));
  gmx1 = fmaxf(gmx1, __shfl_xor(gmx1, 16));
  gmx1 = fmaxf(gmx1, __shfl_xor(gmx1, 32));
  if (l < 16) { gred[0][w][l] = gmx0; gred[1][w][l] = gmx1; }
#pragma unroll
  for (int q = 0; q < 4; ++q) {
    red[0][w][l][q] = a00[q]; red[0][w][l][4 + q] = a01[q];
    red[0][w][l][8 + q] = a02[q]; red[0][w][l][12 + q] = a03[q];
    red[1][w][l][q] = a10[q]; red[1][w][l][4 + q] = a11[q];
    red[1][w][l][8 + q] = a12[q]; red[1][w][l][12 + q] = a13[q];
  }
  __syncthreads();
  const int set = threadIdx.x >> 9;
  const int r9 = threadIdx.x & 511;
  const int tl = r9 & 63, b = (r9 >> 6) & 3, p = r9 >> 8;
  const int idx = (b << 2) + (p << 1);
  float u0 = 0.f, u1 = 0.f;
#pragma unroll
  for (int w16 = 0; w16 < 16; ++w16) {
    u0 += red[set][w16][tl][idx];
    u1 += red[set][w16][tl][idx + 1];
  }
  const int k0r = i0 + (set << 4) + ((tl >> 4) << 2) + (p << 1);
  const unsigned pkv = pack2(f2bf(u0), f2bf(u1));
  const int kbD = k0r >> 5, lgrp = (k0r >> 3) & 3, e0 = k0r & 7;
  *(unsigned*)((char*)Upack +
      ((size_t)((kbD << 2) + b) * 64 + ((tl & 15) | (lgrp << 4))) * 16 + (e0 << 1)) = pkv;
  if (threadIdx.x < 32) {
    const int s2 = threadIdx.x >> 4, rr = threadIdx.x & 15;
    float gm = gred[s2][0][rr];
#pragma unroll
    for (int w16 = 1; w16 < 16; ++w16) gm = fmaxf(gm, gred[s2][w16][rr]);
    Gmax[i0 + (s2 << 4) + rr] = gm;
  }
}

// ---------------- k3: fused softmax + attention@U + ELU; 32 rows/block ----------------
__global__ __launch_bounds__(1024) void k3(const u64* __restrict__ ML,
                                           const unsigned short* __restrict__ Upack,
                                           const float* __restrict__ f,
                                           const float* __restrict__ g,
                                           const float* __restrict__ Gmax,
                                           float* __restrict__ out) {
  __shared__ float red[2][16][64][16];   // 128 KB
  __shared__ float wred[2][16][16];      // 2 KB
  const int l = threadIdx.x & 63;
  const int w = threadIdx.x >> 6;
  const int i0 = blockIdx.x << 5;
  const int r = l & 15, kg = l >> 4;
  const float fi0 = f[i0 + r];
  const float fi1 = f[i0 + 16 + r];
  float m0 = fi0 + Gmax[i0 + r];
  float m1 = fi1 + Gmax[i0 + 16 + r];
  m0 = fmaxf(m0, 0.2f * m0);
  m1 = fmaxf(m1, 0.2f * m1);
  const s16x8* Uv = (const s16x8*)Upack;
  const u64x2* mrow0 = (const u64x2*)(ML + (size_t)(i0 + r) * 128);
  const u64x2* mrow1 = (const u64x2*)(ML + (size_t)(i0 + 16 + r) * 128);
  const int sh0 = kg << 1;
  f32x4 a00 = {0.f,0.f,0.f,0.f}, a01 = a00, a02 = a00, a03 = a00;
  f32x4 a10 = a00, a11 = a00, a12 = a00, a13 = a00;
  float ws0 = 0.f, ws1 = 0.f;
  for (int cc = 0; cc < 2; ++cc) {
    const int c = (w << 1) + cc;
    u64x2 xm01 = mrow0[(c << 1)], xm23 = mrow0[(c << 1) + 1];
    u64x2 ym01 = mrow1[(c << 1)], ym23 = mrow1[(c << 1) + 1];
    const u64 x0 = xm01.x, x1 = xm01.y, x2 = xm23.x, x3 = xm23.y;
    const u64 y0 = ym01.x, y1 = ym01.y, y2 = ym23.x, y3 = ym23.y;
#pragma unroll
    for (int j7 = 0; j7 < 8; ++j7) {
      const int jb = (c << 3) + j7;
      f32x4 g0 = *(const f32x4*)(g + (jb << 5) + (kg << 3));
      f32x4 g1 = *(const f32x4*)(g + (jb << 5) + (kg << 3) + 4);
      const int shb = (j7 << 3) + sh0;
      s16x8 pf0, pf1;
      float wt;
#define K3W(dst, idx2, wq, sh, gv, fi, mm, wsv) {           \
      const unsigned bit_ = (unsigned)((wq) >> (sh)) & 1u;  \
      float x_ = (fi) + (gv);                               \
      float ev_ = fmaxf(x_, 0.2f * x_);                     \
      wt = __expf(ev_ - (mm));                              \
      wt = bit_ ? wt : 0.f;                                 \
      wsv += wt; dst[idx2] = (short)f2bf(wt); }
      K3W(pf0, 0, x0, shb,     g0.x, fi0, m0, ws0)
      K3W(pf0, 1, x1, shb,     g0.y, fi0, m0, ws0)
      K3W(pf0, 2, x2, shb,     g0.z, fi0, m0, ws0)
      K3W(pf0, 3, x3, shb,     g0.w, fi0, m0, ws0)
      K3W(pf0, 4, x0, shb + 1, g1.x, fi0, m0, ws0)
      K3W(pf0, 5, x1, shb + 1, g1.y, fi0, m0, ws0)
      K3W(pf0, 6, x2, shb + 1, g1.z, fi0, m0, ws0)
      K3W(pf0, 7, x3, shb + 1, g1.w, fi0, m0, ws0)
      K3W(pf1, 0, y0, shb,     g0.x, fi1, m1, ws1)
      K3W(pf1, 1, y1, shb,     g0.y, fi1, m1, ws1)
      K3W(pf1, 2, y2, shb,     g0.z, fi1, m1, ws1)
      K3W(pf1, 3, y3, shb,     g0.w, fi1, m1, ws1)
      K3W(pf1, 4, y0, shb + 1, g1.x, fi1, m1, ws1)
      K3W(pf1, 5, y1, shb + 1, g1.y, fi1, m1, ws1)
      K3W(pf1, 6, y2, shb + 1, g1.z, fi1, m1, ws1)
      K3W(pf1, 7, y3, shb + 1, g1.w, fi1, m1, ws1)
#undef K3W
      const size_t bi = ((size_t)jb << 8) + l;
      s16x8 f0 = Uv[bi], f1 = Uv[bi + 64], f2 = Uv[bi + 128], f3 = Uv[bi + 192];
      a00 = MFMA(pf0, f0, a00, 0, 0, 0);
      a01 = MFMA(pf0, f1, a01, 0, 0, 0);
      a02 = MFMA(pf0, f2, a02, 0, 0, 0);
      a03 = MFMA(pf0, f3, a03, 0, 0, 0);
      a10 = MFMA(pf1, f0, a10, 0, 0, 0);
      a11 = MFMA(pf1, f1, a11, 0, 0, 0);
      a12 = MFMA(pf1, f2, a12, 0, 0, 0);
      a13 = MFMA(pf1, f3, a13, 0, 0, 0);
    }
  }
  ws0 += __shfl_xor(ws0, 16);
  ws0 += __shfl_xor(ws0, 32);
  ws1 += __shfl_xor(ws1, 16);
  ws1 += __shfl_xor(ws1, 32);
  if (l < 16) { wred[0][w][l] = ws0; wred[1][w][l] = ws1; }
#pragma unroll
  for (int q = 0; q < 4; ++q) {
    red[0][w][l][q] = a00[q]; red[0][w][l][4 + q] = a01[q];
    red[0][w][l][8 + q] = a02[q]; red[0][w][l][12 + q] = a03[q];
    red[1][w][l][q] = a10[q]; red[1][w][l][4 + q] = a11[q];
    red[1][w][l][8 + q] = a12[q]; red[1][w][l][12 + q] = a13[q];
  }
  __syncthreads();
  const int set = threadIdx.x >> 9;
  const int r9 = threadIdx.x & 511;
  const int tl = r9 & 63, b = (r9 >> 6) & 3, p = r9 >> 8;
#pragma unroll
  for (int q = 0; q < 2; ++q) {
    const int reg = (p << 1) + q;
    const int idx = (b << 2) + reg;
    const int rloc = ((tl >> 4) << 2) + reg;
    float sv = 0.f, dv = 0.f;
#pragma unroll
    for (int w16 = 0; w16 < 16; ++w16) {
      sv += red[set][w16][tl][idx];
      dv += wred[set][w16][rloc];
    }
    dv = (dv > 0.f) ? dv : 1.f;            // defensive: avoid 0/0
    float v = sv / dv;
    v = (v > 0.f) ? v : (__expf(v) - 1.f); // ELU
    out[(size_t)(i0 + (set << 4) + rloc) * 64 + (b << 4) + (tl & 15)] = v;
  }
}

extern "C" void kernel_launch(void* const* d_in, const int* in_sizes, int n_in,
                              void* d_out, int out_size, void* d_ws, size_t ws_size,
                              hipStream_t stream) {
  const float* h   = (const float*)d_in[0];
  const float* adj = (const float*)d_in[1];
  const float* W   = (const float*)d_in[2];
  const float* a   = (const float*)d_in[3];
  float* out = (float*)d_out;
  char* ws = (char*)d_ws;
  unsigned short* Bpack = (unsigned short*)(ws);                     // 1 MB
  unsigned short* Upack = (unsigned short*)(ws + (1u << 20));        // 1 MB
  float* f    = (float*)(ws + (2u << 20));                           // 32 KB
  float* g    = (float*)(ws + (2u << 20) + 32768u);                  // 32 KB
  float* Gmax = (float*)(ws + (2u << 20) + 65536u);                  // 32 KB
  unsigned short* Wfrag = (unsigned short*)(ws + (2u << 20) + 98304u); // 32 KB
  u64* ML = (u64*)(ws + (3u << 20));                                 // 8 MB

  hipLaunchKernelGGL(k0,  dim3(32),   dim3(64),  0, stream, W, Wfrag);
  hipLaunchKernelGGL(k1,  dim3(512),  dim3(64),  0, stream, h, Wfrag, a, Bpack, f, g);
  hipLaunchKernelGGL(k2a, dim3(2048), dim3(256), 0, stream, adj, ML);
  hipLaunchKernelGGL(k2b, dim3(256),  dim3(1024), 0, stream, ML, Bpack, g, Upack, Gmax);
  hipLaunchKernelGGL(k3,  dim3(256),  dim3(1024), 0, stream, ML, Upack, f, g, Gmax, out);
}

// Round 7
// 139.701 us; speedup vs baseline: 1.2593x; 1.2593x over previous
//
#include <hip/hip_runtime.h>
#include <hip/hip_bf16.h>

// GAT layer, N=8192, F_IN=256, F_OUT=64.
//  kA : fused independent stages, role by blockIdx parity:
//       even bid -> k2a role: pure-stream mask builder (one adj row per wave).
//         ML[i][c][q] bit l = adj[i][c*256 + l*4 + q] > 0.
//       odd bid  -> k1 role: scalar Wh = h@W; f,g projections; Bpack (bf16
//         B-frags of Wh).  (round-5-proven bodies, verbatim)
//  k2b: U = adj@Wh from bitmask via MFMA; masked Gmax; Upack direct. 16 rows/blk.
//  k3 : fused softmax weights + attention@U via MFMA + denominator; ELU.
//
// Fragment convention (proven rounds 1/3/4/5):
//  element e of lane l <-> k = kblock*32 + (l>>4)*8 + e; A row / B col = l&15;
//  C/D: col = l&15, row = (l>>4)*4 + reg.
//  Bpack/Upack: frag[(kb*4+b)*64 + lane][e]  (s16x8 per lane)
// Mask bit for (row i, col j): word ML[i*128 + (j>>8)*4 + (j&3)], bit (j>>2)&63.
//  For fragment element (r, jb, kg, e): word (jb>>3)*4 + (e&3),
//  shift = (jb&7)*8 + kg*2 + (e>>2).

#define N 8192

typedef float f32x4 __attribute__((ext_vector_type(4)));
typedef short s16x8 __attribute__((ext_vector_type(8)));
typedef unsigned long long u64;
typedef u64 u64x2 __attribute__((ext_vector_type(2)));

__device__ __forceinline__ unsigned short f2bf(float x) {
  unsigned u = __float_as_uint(x);
  u += 0x7FFFu + ((u >> 16) & 1u);   // RNE
  return (unsigned short)(u >> 16);
}
__device__ __forceinline__ unsigned pack2(unsigned short lo, unsigned short hi) {
  return (unsigned)lo | ((unsigned)hi << 16);
}

#define MFMA __builtin_amdgcn_mfma_f32_16x16x32_bf16

// ---------------- kA: fused k2a (even bid) + k1 (odd bid) ----------------
__global__ __launch_bounds__(256) void kA(const float* __restrict__ adj,
                                          const float* __restrict__ h,
                                          const float* __restrict__ W,
                                          const float* __restrict__ a,
                                          u64* __restrict__ ML,
                                          unsigned short* __restrict__ Bpack,
                                          float* __restrict__ f,
                                          float* __restrict__ g) {
  const int l = threadIdx.x & 63;
  const int w = threadIdx.x >> 6;
  const int bid = blockIdx.x;
  if ((bid & 1) == 0) {
    // ----- k2a role (round-5-proven body) -----
    const int i = ((bid >> 1) << 2) + w;   // one row per wave
    const float* ap = adj + (size_t)i * N + (l << 2);
    u64* mp = ML + (size_t)i * 128;
    for (int cc = 0; cc < 32; cc += 4) {
      f32x4 v0 = *(const f32x4*)(ap + ((cc + 0) << 8));
      f32x4 v1 = *(const f32x4*)(ap + ((cc + 1) << 8));
      f32x4 v2 = *(const f32x4*)(ap + ((cc + 2) << 8));
      f32x4 v3 = *(const f32x4*)(ap + ((cc + 3) << 8));
      u64 b0  = __ballot(v0.x > 0.f), b1  = __ballot(v0.y > 0.f);
      u64 b2  = __ballot(v0.z > 0.f), b3  = __ballot(v0.w > 0.f);
      u64 b4  = __ballot(v1.x > 0.f), b5  = __ballot(v1.y > 0.f);
      u64 b6  = __ballot(v1.z > 0.f), b7  = __ballot(v1.w > 0.f);
      u64 b8  = __ballot(v2.x > 0.f), b9  = __ballot(v2.y > 0.f);
      u64 b10 = __ballot(v2.z > 0.f), b11 = __ballot(v2.w > 0.f);
      u64 b12 = __ballot(v3.x > 0.f), b13 = __ballot(v3.y > 0.f);
      u64 b14 = __ballot(v3.z > 0.f), b15 = __ballot(v3.w > 0.f);
      if (l == 0) {
        u64x2* q = (u64x2*)(mp + (cc << 2));
        u64x2 t0; t0.x = b0;  t0.y = b1;  q[0] = t0;
        u64x2 t1; t1.x = b2;  t1.y = b3;  q[1] = t1;
        u64x2 t2; t2.x = b4;  t2.y = b5;  q[2] = t2;
        u64x2 t3; t3.x = b6;  t3.y = b7;  q[3] = t3;
        u64x2 t4; t4.x = b8;  t4.y = b9;  q[4] = t4;
        u64x2 t5; t5.x = b10; t5.y = b11; q[5] = t5;
        u64x2 t6; t6.x = b12; t6.y = b13; q[6] = t6;
        u64x2 t7; t7.x = b14; t7.y = b15; q[7] = t7;
      }
    }
  } else {
    // ----- k1 role (round-5-proven body) -----
    const int i = ((bid >> 1) << 2) + w;   // row
    const float* hrow = h + (size_t)i * 256;
    float acc = 0.f;
#pragma unroll 4
    for (int kb = 0; kb < 64; ++kb) {
      f32x4 hv = *(const f32x4*)(hrow + (kb << 2));
      acc += hv.x * W[((kb << 2) + 0) * 64 + l];
      acc += hv.y * W[((kb << 2) + 1) * 64 + l];
      acc += hv.z * W[((kb << 2) + 2) * 64 + l];
      acc += hv.w * W[((kb << 2) + 3) * 64 + l];
    }
    float s1 = acc * a[l];
    float s2 = acc * a[64 + l];
#pragma unroll
    for (int d = 32; d > 0; d >>= 1) {
      s1 += __shfl_xor(s1, d);
      s2 += __shfl_xor(s2, d);
    }
    if (l == 0) { f[i] = s1; g[i] = s2; }
    const int kb = i >> 5;
    const int b = l >> 4;
    const int lp = (l & 15) | (((i >> 3) & 3) << 4);
    const int e = i & 7;
    Bpack[(((size_t)(kb * 4 + b)) * 64 + lp) * 8 + e] = f2bf(acc);
  }
}

// ---------------- k2b: U = adj@Wh from mask + Gmax; Upack direct ----------------
__global__ __launch_bounds__(512, 4) void k2b(const u64* __restrict__ ML,
                                              const unsigned short* __restrict__ Bpack,
                                              const float* __restrict__ g,
                                              unsigned short* __restrict__ Upack,
                                              float* __restrict__ Gmax) {
  __shared__ float red[8][64][16];   // 32 KB
  __shared__ float gred[8][16];
  const int l = threadIdx.x & 63;
  const int w = threadIdx.x >> 6;
  const int i0 = blockIdx.x << 4;          // 16 rows/block
  const int r = l & 15, kg = l >> 4;
  const s16x8* Bv = (const s16x8*)Bpack;
  const u64x2* mrow = (const u64x2*)(ML + (size_t)(i0 + r) * 128);
  const int sh0 = kg << 1;
  f32x4 acc0 = {0.f,0.f,0.f,0.f}, acc1 = acc0, acc2 = acc0, acc3 = acc0;
  float gmx = -INFINITY;
  for (int cc = 0; cc < 4; ++cc) {
    const int c = (w << 2) + cc;           // chunk of 256 cols
    u64x2 m01 = mrow[(c << 1)], m23 = mrow[(c << 1) + 1];
    const u64 wq0 = m01.x, wq1 = m01.y, wq2 = m23.x, wq3 = m23.y;
#pragma unroll
    for (int j7 = 0; j7 < 8; ++j7) {
      const int jb = (c << 3) + j7;
      f32x4 g0 = *(const f32x4*)(g + (jb << 5) + (kg << 3));
      f32x4 g1 = *(const f32x4*)(g + (jb << 5) + (kg << 3) + 4);
      const int shb = (j7 << 3) + sh0;
      const unsigned bit0 = (unsigned)(wq0 >> shb) & 1u;
      const unsigned bit1 = (unsigned)(wq1 >> shb) & 1u;
      const unsigned bit2 = (unsigned)(wq2 >> shb) & 1u;
      const unsigned bit3 = (unsigned)(wq3 >> shb) & 1u;
      const unsigned bit4 = (unsigned)(wq0 >> (shb + 1)) & 1u;
      const unsigned bit5 = (unsigned)(wq1 >> (shb + 1)) & 1u;
      const unsigned bit6 = (unsigned)(wq2 >> (shb + 1)) & 1u;
      const unsigned bit7 = (unsigned)(wq3 >> (shb + 1)) & 1u;
      s16x8 af;
      af[0] = bit0 ? (short)0x3F80 : (short)0;
      af[1] = bit1 ? (short)0x3F80 : (short)0;
      af[2] = bit2 ? (short)0x3F80 : (short)0;
      af[3] = bit3 ? (short)0x3F80 : (short)0;
      af[4] = bit4 ? (short)0x3F80 : (short)0;
      af[5] = bit5 ? (short)0x3F80 : (short)0;
      af[6] = bit6 ? (short)0x3F80 : (short)0;
      af[7] = bit7 ? (short)0x3F80 : (short)0;
      if (bit0) gmx = fmaxf(gmx, g0.x);
      if (bit1) gmx = fmaxf(gmx, g0.y);
      if (bit2) gmx = fmaxf(gmx, g0.z);
      if (bit3) gmx = fmaxf(gmx, g0.w);
      if (bit4) gmx = fmaxf(gmx, g1.x);
      if (bit5) gmx = fmaxf(gmx, g1.y);
      if (bit6) gmx = fmaxf(gmx, g1.z);
      if (bit7) gmx = fmaxf(gmx, g1.w);
      const size_t bi = ((size_t)jb << 8) + l;
      s16x8 f0 = Bv[bi], f1 = Bv[bi + 64], f2 = Bv[bi + 128], f3 = Bv[bi + 192];
      acc0 = MFMA(af, f0, acc0, 0, 0, 0);
      acc1 = MFMA(af, f1, acc1, 0, 0, 0);
      acc2 = MFMA(af, f2, acc2, 0, 0, 0);
      acc3 = MFMA(af, f3, acc3, 0, 0, 0);
    }
  }
  gmx = fmaxf(gmx, __shfl_xor(gmx, 16));
  gmx = fmaxf(gmx, __shfl_xor(gmx, 32));
  if (l < 16) gred[w][l] = gmx;
#pragma unroll
  for (int q = 0; q < 4; ++q) {
    red[w][l][q] = acc0[q]; red[w][l][4 + q] = acc1[q];
    red[w][l][8 + q] = acc2[q]; red[w][l][12 + q] = acc3[q];
  }
  __syncthreads();
  const int tl = threadIdx.x & 63;
  const int b = (threadIdx.x >> 6) & 3;
  const int sE = threadIdx.x >> 8;
  const int reg0 = sE << 1;
  float u0 = 0.f, u1 = 0.f;
#pragma unroll
  for (int w8 = 0; w8 < 8; ++w8) {
    u0 += red[w8][tl][(b << 2) + reg0];
    u1 += red[w8][tl][(b << 2) + reg0 + 1];
  }
  const int k0 = i0 + ((tl >> 4) << 2) + reg0;
  const unsigned pkv = pack2(f2bf(u0), f2bf(u1));
  const int kbD = k0 >> 5, lgrp = (k0 >> 3) & 3, e0 = k0 & 7;
  *(unsigned*)((char*)Upack +
      ((size_t)((kbD << 2) + b) * 64 + ((tl & 15) | (lgrp << 4))) * 16 + (e0 << 1)) = pkv;
  if (threadIdx.x < 16) {
    float gm = gred[0][threadIdx.x];
#pragma unroll
    for (int w8 = 1; w8 < 8; ++w8) gm = fmaxf(gm, gred[w8][threadIdx.x]);
    Gmax[i0 + threadIdx.x] = gm;
  }
}

// ---------------- k3: fused softmax + attention@U + ELU ----------------
__global__ __launch_bounds__(512, 4) void k3(const u64* __restrict__ ML,
                                             const unsigned short* __restrict__ Upack,
                                             const float* __restrict__ f,
                                             const float* __restrict__ g,
                                             const float* __restrict__ Gmax,
                                             float* __restrict__ out) {
  __shared__ float red[8][64][16];   // 32 KB
  __shared__ float wred[8][16];
  const int l = threadIdx.x & 63;
  const int w = threadIdx.x >> 6;
  const int i0 = blockIdx.x << 4;
  const int r = l & 15, kg = l >> 4;
  const float fi = f[i0 + r];
  float m = fi + Gmax[i0 + r];
  m = fmaxf(m, 0.2f * m);                  // m_i = leaky(f_i + Gmax_i)
  const s16x8* Uv = (const s16x8*)Upack;
  const u64x2* mrow = (const u64x2*)(ML + (size_t)(i0 + r) * 128);
  const int sh0 = kg << 1;
  f32x4 acc0 = {0.f,0.f,0.f,0.f}, acc1 = acc0, acc2 = acc0, acc3 = acc0;
  float wsum = 0.f;
  for (int cc = 0; cc < 4; ++cc) {
    const int c = (w << 2) + cc;
    u64x2 m01 = mrow[(c << 1)], m23 = mrow[(c << 1) + 1];
    const u64 wq0 = m01.x, wq1 = m01.y, wq2 = m23.x, wq3 = m23.y;
#pragma unroll
    for (int j7 = 0; j7 < 8; ++j7) {
      const int jb = (c << 3) + j7;
      f32x4 g0 = *(const f32x4*)(g + (jb << 5) + (kg << 3));
      f32x4 g1 = *(const f32x4*)(g + (jb << 5) + (kg << 3) + 4);
      const int shb = (j7 << 3) + sh0;
      s16x8 pf;
      float wt;
#define K3W(idx, wq, sh, gv) {                                  \
      const unsigned bit_ = (unsigned)((wq) >> (sh)) & 1u;      \
      float x_ = fi + (gv);                                     \
      float ev_ = fmaxf(x_, 0.2f * x_);                         \
      wt = __expf(ev_ - m);                                     \
      wt = bit_ ? wt : 0.f;                                     \
      wsum += wt; pf[idx] = (short)f2bf(wt); }
      K3W(0, wq0, shb,     g0.x)
      K3W(1, wq1, shb,     g0.y)
      K3W(2, wq2, shb,     g0.z)
      K3W(3, wq3, shb,     g0.w)
      K3W(4, wq0, shb + 1, g1.x)
      K3W(5, wq1, shb + 1, g1.y)
      K3W(6, wq2, shb + 1, g1.z)
      K3W(7, wq3, shb + 1, g1.w)
#undef K3W
      const size_t bi = ((size_t)jb << 8) + l;
      s16x8 f0 = Uv[bi], f1 = Uv[bi + 64], f2 = Uv[bi + 128], f3 = Uv[bi + 192];
      acc0 = MFMA(pf, f0, acc0, 0, 0, 0);
      acc1 = MFMA(pf, f1, acc1, 0, 0, 0);
      acc2 = MFMA(pf, f2, acc2, 0, 0, 0);
      acc3 = MFMA(pf, f3, acc3, 0, 0, 0);
    }
  }
  wsum += __shfl_xor(wsum, 16);
  wsum += __shfl_xor(wsum, 32);
  if (l < 16) wred[w][l] = wsum;
#pragma unroll
  for (int q = 0; q < 4; ++q) {
    red[w][l][q] = acc0[q]; red[w][l][4 + q] = acc1[q];
    red[w][l][8 + q] = acc2[q]; red[w][l][12 + q] = acc3[q];
  }
  __syncthreads();
  const int tl = threadIdx.x & 63;
  const int b = (threadIdx.x >> 6) & 3;
  const int sE = threadIdx.x >> 8;
#pragma unroll
  for (int q = 0; q < 2; ++q) {
    const int reg = (sE << 1) + q;
    const int idx = (b << 2) + reg;
    const int row = ((tl >> 4) << 2) + reg;
    float sv = 0.f, dv = 0.f;
#pragma unroll
    for (int w8 = 0; w8 < 8; ++w8) {
      sv += red[w8][tl][idx];
      dv += wred[w8][row];
    }
    dv = (dv > 0.f) ? dv : 1.f;            // defensive: avoid 0/0
    float v = sv / dv;
    v = (v > 0.f) ? v : (__expf(v) - 1.f); // ELU
    out[(size_t)(i0 + row) * 64 + (b << 4) + (tl & 15)] = v;
  }
}

extern "C" void kernel_launch(void* const* d_in, const int* in_sizes, int n_in,
                              void* d_out, int out_size, void* d_ws, size_t ws_size,
                              hipStream_t stream) {
  const float* h   = (const float*)d_in[0];
  const float* adj = (const float*)d_in[1];
  const float* W   = (const float*)d_in[2];
  const float* a   = (const float*)d_in[3];
  float* out = (float*)d_out;
  char* ws = (char*)d_ws;
  unsigned short* Bpack = (unsigned short*)(ws);                   // 1 MB
  unsigned short* Upack = (unsigned short*)(ws + (1u << 20));      // 1 MB
  float* f    = (float*)(ws + (2u << 20));                         // 32 KB
  float* g    = (float*)(ws + (2u << 20) + 32768u);                // 32 KB
  float* Gmax = (float*)(ws + (2u << 20) + 65536u);                // 32 KB
  u64* ML = (u64*)(ws + (3u << 20));                               // 8 MB

  hipLaunchKernelGGL(kA,  dim3(4096), dim3(256), 0, stream, adj, h, W, a, ML, Bpack, f, g);
  hipLaunchKernelGGL(k2b, dim3(512),  dim3(512), 0, stream, ML, Bpack, g, Upack, Gmax);
  hipLaunchKernelGGL(k3,  dim3(512),  dim3(512), 0, stream, ML, Upack, f, g, Gmax, out);
}